// Round 7
// baseline (974.551 us; speedup 1.0000x reference)
//
#include <hip/hip_runtime.h>
#include <stdint.h>

#define Bn 4
#define Sn 2048
#define Hn 1024
#define Ln 4
#define Mn (Bn*Sn)          // 8192 rows
#define CHUNK 32
#define NCH (Sn/CHUNK)      // 64

typedef __bf16 bf16x8 __attribute__((ext_vector_type(8)));
typedef float  f32x4  __attribute__((ext_vector_type(4)));
typedef uint32_t u32;

__device__ __forceinline__ unsigned short f2bf(float f) {
  uint32_t u = __float_as_uint(f);
  uint32_t r = (u + 0x7FFFu + ((u >> 16) & 1u)) >> 16;
  return (unsigned short)r;
}
__device__ __forceinline__ float bf2f(unsigned short u) {
  return __uint_as_float(((uint32_t)u) << 16);
}

__device__ __forceinline__ void gload_lds16(const void* g, void* l) {
  __builtin_amdgcn_global_load_lds((const __attribute__((address_space(1))) void*)g,
                                   (__attribute__((address_space(3))) void*)l, 16, 0, 0);
}

// ---------------- cast f32 -> bf16 (vectorized) ----------------
__global__ __launch_bounds__(256) void cast_f32_bf16(const float* __restrict__ src,
                                                     unsigned short* __restrict__ dst, int n4) {
  int i = blockIdx.x * 256 + threadIdx.x;
  if (i >= n4) return;
  float4 v = reinterpret_cast<const float4*>(src)[i];
  ushort4 o;
  o.x = f2bf(v.x); o.y = f2bf(v.y); o.z = f2bf(v.z); o.w = f2bf(v.w);
  reinterpret_cast<ushort4*>(dst)[i] = o;
}

// ---------------- GEMM: out[M,N] = act[M,K](bf16) @ W[N,K]^T (bf16) + bias ----------------
// ROUND-7: tile 256x128, BK=32, 48 KB LDS -> 2 blocks/CU co-resident (VGPR-limited).
// Rounds 1-6 ran 256x256 / 128 KB LDS = exactly 1 block/CU; with 8 barrier-synced
// waves and nothing else resident, every lgkm/vmcnt/barrier was idle SIMD time —
// the invariant ~6000 excess cyc/K-tile across three different sync schedules.
// m97's 37% MfmaUtil had ~3 blocks/CU; co-residency is the missing ingredient.
// Layer grid: 512 blocks = 2/CU. Fusion grid: 256 blocks = all CUs busy (the old
// BN=256 fusion ran 128 blocks -> HALF THE MACHINE IDLE; it was the top-5 dispatch).
//
// 8 waves: waveM=w>>1 (0..3, 64 rows each), waveN=w&1 (0..1, 64 cols each).
// LDS per matrix: [2 buf][rows][64 B] — A: 256 rows (16 KB/buf), B: 128 rows (8 KB/buf).
// Swizzle: phys_slot = logical_slot ^ ((row>>1)&3), 2-way (free); linear DMA dest,
// inverse-permuted global source, same XOR on ds_read (rule #21).
// Chunked XCD swizzle (nwg%8==0 -> bijective): consecutive swizzled ids share a
// B-panel and stay on one XCD's L2.
// Per K-tile: 3 gload_lds + 8 asm ds_read_b128 + LGKM(3/2/1/0)-pipelined 4 MFMA rows
// + vmcnt(0) + 1 barrier. K-slice accumulation order (k ascending) identical to all
// prior rounds -> bit-identical output.

#define DSR(d, b, imm) \
  asm volatile("ds_read_b128 %0, %1 offset:%c2" : "=&v"(d) : "v"(b), "i"(imm))

__global__ __launch_bounds__(512, 2) void gemm128(
    const unsigned short* __restrict__ act,  // M x K
    const unsigned short* __restrict__ Wlo,  // rows [0, Nsplit)
    const unsigned short* __restrict__ Whi,  // rows [Nsplit, N)
    const float* __restrict__ bias0, const float* __restrict__ bias1,
    int Nsplit, float* __restrict__ out, unsigned short* __restrict__ outbf,
    int Ndim, int K) {
  __shared__ unsigned char smA[32768];   // 2 buf x 256 rows x 64 B
  __shared__ unsigned char smB[16384];   // 2 buf x 128 rows x 64 B
  const int tid  = threadIdx.x;
  const int lane = tid & 63;
  const int w    = tid >> 6;           // 0..7
  const int waveM = w >> 1;            // 0..3  (64 rows each)
  const int waveN = w & 1;             // 0..1  (64 cols each)

  // chunked XCD swizzle (requires gridDim.x % 8 == 0; 512 and 256 both qualify)
  const int nwg = gridDim.x;
  const int bid = blockIdx.x;
  const int sid = (bid & 7) * (nwg >> 3) + (bid >> 3);
  const int bm = sid & 31;             // Mn/256 = 32 always
  const int bn = sid >> 5;

  const unsigned short* Wp; int nbase;
  if (bn * 128 < Nsplit) { Wp = Wlo; nbase = bn * 128; }
  else                   { Wp = Whi; nbase = bn * 128 - Nsplit; }

  // per-lane ds_read byte offsets within a buf region
  const int swz  = (((lane >> 4) ^ ((lane >> 1) & 3)) << 4);
  const int aoff = (waveM * 64 + (lane & 15)) * 64 + swz;   // < 16 KB
  const int boff = (waveN * 64 + (lane & 15)) * 64 + swz;   // < 8 KB

  const u32 baseA = (u32)(size_t)(void*)&smA[0] + (u32)aoff;
  const u32 baseB = (u32)(size_t)(void*)&smB[0] + (u32)boff;

  // staging: thread -> phys (row = tid>>2 within 128-row half, slot = tid&3);
  // fetch the logical slot belonging at that phys position: log = phys ^ ((row>>1)&3)
  const int srow = tid >> 2;           // 0..127
  const int slog = (tid & 3) ^ ((srow >> 1) & 3);
  const unsigned short* aS0 = act + (size_t)(bm * 256 + srow) * K + slog * 8;
  const unsigned short* aS1 = aS0 + (size_t)128 * K;
  const unsigned short* bS0 = Wp  + (size_t)(nbase + srow) * K + slog * 8;
  const int wB = w * 1024;             // wave-uniform LDS byte base within an 8KB round

  f32x4 acc[4][4];
#pragma unroll
  for (int m = 0; m < 4; ++m)
#pragma unroll
    for (int n = 0; n < 4; ++n) acc[m][n] = (f32x4)0.0f;

  bf16x8 aA[4], b0[4];

#define STG3(t, buf) do { \
    gload_lds16(aS0 + (size_t)(t) * 32, smA + (buf) * 16384 + wB); \
    gload_lds16(aS1 + (size_t)(t) * 32, smA + (buf) * 16384 + 8192 + wB); \
    gload_lds16(bS0 + (size_t)(t) * 32, smB + (buf) * 8192 + wB); \
  } while (0)

#define VMW(n) do { \
    asm volatile("s_waitcnt vmcnt(" #n ")"); \
    __builtin_amdgcn_sched_barrier(0); \
  } while (0)

#define LGKM(n) do { \
    asm volatile("s_waitcnt lgkmcnt(" #n ")"); \
    __builtin_amdgcn_sched_barrier(0); \
  } while (0)

#define ROW(m) do { \
    __builtin_amdgcn_s_setprio(1); \
    _Pragma("unroll") \
    for (int _n = 0; _n < 4; ++_n) \
      acc[m][_n] = __builtin_amdgcn_mfma_f32_16x16x32_bf16( \
          aA[m], b0[_n], acc[m][_n], 0, 0, 0); \
    __builtin_amdgcn_s_setprio(0); \
  } while (0)

// per-tile compute: issue all 8 reads, then LGKM-pipelined MFMA rows
// (LGKM(3): b0[0..3]+aA[0] retired; each later row waits one more aA)
#define BODY(buf) do { \
    DSR(b0[0], baseB, (buf) * 8192 + 0); \
    DSR(b0[1], baseB, (buf) * 8192 + 1024); \
    DSR(b0[2], baseB, (buf) * 8192 + 2048); \
    DSR(b0[3], baseB, (buf) * 8192 + 3072); \
    DSR(aA[0], baseA, (buf) * 16384 + 0); \
    DSR(aA[1], baseA, (buf) * 16384 + 1024); \
    DSR(aA[2], baseA, (buf) * 16384 + 2048); \
    DSR(aA[3], baseA, (buf) * 16384 + 3072); \
    LGKM(3); ROW(0); \
    LGKM(2); ROW(1); \
    LGKM(1); ROW(2); \
    LGKM(0); ROW(3); \
  } while (0)

  const int nkt   = K >> 5;   // K-tiles of 32 (layer 32, fusion 64)
  const int niter = nkt >> 1;

  // prologue: stage tile 0 into buf0
  STG3(0, 0);
  VMW(0);
  __builtin_amdgcn_s_barrier();

  for (int j = 0; j < niter - 1; ++j) {
    STG3(2 * j + 1, 1); BODY(0); VMW(0); __builtin_amdgcn_s_barrier();
    STG3(2 * j + 2, 0); BODY(1); VMW(0); __builtin_amdgcn_s_barrier();
  }
  STG3(nkt - 1, 1); BODY(0); VMW(0); __builtin_amdgcn_s_barrier();
  BODY(1);

#undef BODY
#undef ROW
#undef LGKM
#undef VMW
#undef STG3

  const int colBase = bn * 128 + waveN * 64;
  const int rowBase = bm * 256 + waveM * 64;
#pragma unroll
  for (int m = 0; m < 4; ++m) {
#pragma unroll
    for (int n = 0; n < 4; ++n) {
      int col = colBase + n * 16 + (lane & 15);
      float bv = (col < Nsplit) ? bias0[col] : bias1[col - Nsplit];
      if (outbf) {
#pragma unroll
        for (int r = 0; r < 4; ++r) {
          int row = rowBase + m * 16 + (lane >> 4) * 4 + r;
          outbf[(size_t)row * Ndim + col] = f2bf(acc[m][n][r] + bv);
        }
      } else {
#pragma unroll
        for (int r = 0; r < 4; ++r) {
          int row = rowBase + m * 16 + (lane >> 4) * 4 + r;
          out[(size_t)row * Ndim + col] = acc[m][n][r] + bv;
        }
      }
    }
  }
}

// ---------------- pointwise helpers ----------------
__device__ __forceinline__ void gate_ab(float zp, float hp, float& a, float& bv) {
  float z  = 1.0f / (1.0f + __expf(-zp));
  float e  = __expf(-2.0f * fabsf(hp));
  float th = (1.0f - e) / (1.0f + e);
  th = (hp >= 0.0f) ? th : -th;
  a  = fminf(fmaxf(1.0f - z, 1e-8f), 1.0f - 1e-8f);
  bv = z * th;
}

// ---------------- scan pass 1: per-chunk composition (bf16 pre) ----------------
__global__ __launch_bounds__(256) void scan_p1(const unsigned short* __restrict__ pre,
                                               float* __restrict__ Ac, float* __restrict__ Bc,
                                               int dir) {
  int tid = threadIdx.x;
  int bid = blockIdx.x;
  int ht = bid & 3;
  int c  = (bid >> 2) & (NCH - 1);
  int b  = bid >> 8;
  int h  = ht * 256 + tid;
  float Aa = 1.0f, Bb = 0.0f;
  for (int j = 0; j < CHUNK; ++j) {
    int t = c * CHUNK + j;
    int s = dir ? (Sn - 1 - t) : t;
    const unsigned short* p = pre + (size_t)(b * Sn + s) * 2048;
    float a, bv;
    gate_ab(bf2f(p[h]), bf2f(p[1024 + h]), a, bv);
    Aa = a * Aa;
    Bb = a * Bb + bv;
  }
  Ac[(size_t)(b * NCH + c) * Hn + h] = Aa;
  Bc[(size_t)(b * NCH + c) * Hn + h] = Bb;
}

// ---------------- scan mid: prefix across chunks ----------------
__global__ __launch_bounds__(256) void scan_mid(const float* __restrict__ Ac,
                                                const float* __restrict__ Bc,
                                                float* __restrict__ pref) {
  int tid = blockIdx.x * 256 + threadIdx.x;
  int b = tid >> 10;
  int h = tid & 1023;
  float run = 0.0f;
  for (int c = 0; c < NCH; ++c) {
    size_t idx = (size_t)(b * NCH + c) * Hn + h;
    pref[idx] = run;
    run = Ac[idx] * run + Bc[idx];
  }
}

// ---------------- scan pass 3: apply (bf16 pre) ----------------
__global__ __launch_bounds__(256) void scan_p3(const unsigned short* __restrict__ pre,
                                               const float* __restrict__ pref,
                                               float* __restrict__ hs, int dir) {
  int tid = threadIdx.x;
  int bid = blockIdx.x;
  int ht = bid & 3;
  int c  = (bid >> 2) & (NCH - 1);
  int b  = bid >> 8;
  int h  = ht * 256 + tid;
  float hprev = pref[(size_t)(b * NCH + c) * Hn + h];
  for (int j = 0; j < CHUNK; ++j) {
    int t = c * CHUNK + j;
    int s = dir ? (Sn - 1 - t) : t;
    const unsigned short* p = pre + (size_t)(b * Sn + s) * 2048;
    float a, bv;
    gate_ab(bf2f(p[h]), bf2f(p[1024 + h]), a, bv);
    hprev = a * hprev + bv;
    hs[(size_t)(b * Sn + s) * Hn + h] = hprev;
  }
}

// ---------------- LayerNorm (+residual), writes f32 + bf16 ----------------
__global__ __launch_bounds__(256) void ln_kernel(const float* __restrict__ hs,
                                                 const float* __restrict__ resid,
                                                 const float* __restrict__ gamma,
                                                 const float* __restrict__ beta,
                                                 float* __restrict__ out_f32,
                                                 unsigned short* __restrict__ out_bf,
                                                 int bf_stride, int bf_off) {
  int row  = blockIdx.x * 4 + (threadIdx.x >> 6);
  int lane = threadIdx.x & 63;
  const float4* hr = reinterpret_cast<const float4*>(hs + (size_t)row * Hn);
  const float4* rr = resid ? reinterpret_cast<const float4*>(resid + (size_t)row * Hn) : nullptr;
  float v[16];
  float s1 = 0.0f, s2 = 0.0f;
#pragma unroll
  for (int j = 0; j < 4; ++j) {
    float4 t = hr[j * 64 + lane];
    if (rr) {
      float4 q = rr[j * 64 + lane];
      t.x += q.x; t.y += q.y; t.z += q.z; t.w += q.w;
    }
    v[j*4+0] = t.x; v[j*4+1] = t.y; v[j*4+2] = t.z; v[j*4+3] = t.w;
    s1 += t.x + t.y + t.z + t.w;
    s2 += t.x*t.x + t.y*t.y + t.z*t.z + t.w*t.w;
  }
#pragma unroll
  for (int off = 1; off < 64; off <<= 1) {
    s1 += __shfl_xor(s1, off);
    s2 += __shfl_xor(s2, off);
  }
  float mu  = s1 * (1.0f / Hn);
  float var = s2 * (1.0f / Hn) - mu * mu;
  float rs  = rsqrtf(var + 1e-5f);
#pragma unroll
  for (int j = 0; j < 4; ++j) {
    float4 g  = reinterpret_cast<const float4*>(gamma)[j * 64 + lane];
    float4 be = reinterpret_cast<const float4*>(beta)[j * 64 + lane];
    float4 o;
    o.x = (v[j*4+0] - mu) * rs * g.x + be.x;
    o.y = (v[j*4+1] - mu) * rs * g.y + be.y;
    o.z = (v[j*4+2] - mu) * rs * g.z + be.z;
    o.w = (v[j*4+3] - mu) * rs * g.w + be.w;
    if (out_f32)
      reinterpret_cast<float4*>(out_f32 + (size_t)row * Hn)[j * 64 + lane] = o;
    ushort4 ob;
    ob.x = f2bf(o.x); ob.y = f2bf(o.y); ob.z = f2bf(o.z); ob.w = f2bf(o.w);
    reinterpret_cast<ushort4*>(out_bf + (size_t)row * bf_stride + bf_off)[j * 64 + lane] = ob;
  }
}

// ---------------- launcher ----------------
extern "C" void kernel_launch(void* const* d_in, const int* in_sizes, int n_in,
                              void* d_out, int out_size, void* d_ws, size_t ws_size,
                              hipStream_t stream) {
  const float* x        = (const float*)d_in[0];
  const float* fwd_Wz   = (const float*)d_in[1];
  const float* fwd_bz   = (const float*)d_in[2];
  const float* fwd_Wh   = (const float*)d_in[3];
  const float* fwd_bh   = (const float*)d_in[4];
  const float* bwd_Wz   = (const float*)d_in[5];
  const float* bwd_bz   = (const float*)d_in[6];
  const float* bwd_Wh   = (const float*)d_in[7];
  const float* bwd_bh   = (const float*)d_in[8];
  const float* fusion_W = (const float*)d_in[9];
  const float* fusion_b = (const float*)d_in[10];
  const float* gamma    = (const float*)d_in[11];
  const float* beta     = (const float*)d_in[12];
  float* out = (float*)d_out;

  // workspace layout (pre slot holds bf16 pre-activations, 33.5 MB of its 67 MB)
  unsigned short* WzA    = (unsigned short*)d_ws;              // 2*4*1024*1024
  unsigned short* WhA    = WzA + 8ULL * 1024 * 1024;           // 2*4*1024*1024
  unsigned short* fusWbf = WhA + 8ULL * 1024 * 1024;           // 1024*2048
  unsigned short* xbf    = fusWbf + 2ULL * 1024 * 1024;        // 8192*1024
  unsigned short* actbf  = xbf + 8ULL * 1024 * 1024;           // 8192*1024
  unsigned short* combbf = actbf + 8ULL * 1024 * 1024;         // 8192*2048
  float* actf = (float*)(combbf + 16ULL * 1024 * 1024);        // 8192*1024
  float* pre  = actf + 8ULL * 1024 * 1024;                     // 8192*2048 (bf16 uses half)
  float* hs   = pre + 16ULL * 1024 * 1024;                     // 8192*1024
  float* Ac   = hs + 8ULL * 1024 * 1024;                       // 4*NCH*1024
  float* Bc   = Ac + (size_t)Bn * NCH * Hn;
  float* pref = Bc + (size_t)Bn * NCH * Hn;
  size_t need = (size_t)((char*)(pref + (size_t)Bn * NCH * Hn) - (char*)d_ws);
  if (ws_size < need) return;
  unsigned short* prebf = (unsigned short*)pre;

  auto cast = [&](const float* src, unsigned short* dst, size_t n) {
    int n4 = (int)(n / 4);
    cast_f32_bf16<<<(n4 + 255) / 256, 256, 0, stream>>>(src, dst, n4);
  };
  cast(fwd_Wz, WzA,                     4ULL * 1024 * 1024);
  cast(bwd_Wz, WzA + 4ULL * 1024 * 1024, 4ULL * 1024 * 1024);
  cast(fwd_Wh, WhA,                     4ULL * 1024 * 1024);
  cast(bwd_Wh, WhA + 4ULL * 1024 * 1024, 4ULL * 1024 * 1024);
  cast(fusion_W, fusWbf, 2ULL * 1024 * 1024);
  cast(x, xbf, 8ULL * 1024 * 1024);

  for (int d = 0; d < 2; ++d) {
    const float* bz = d ? bwd_bz : fwd_bz;
    const float* bh = d ? bwd_bh : fwd_bh;
    for (int l = 0; l < Ln; ++l) {
      const unsigned short* a_in = (l == 0) ? xbf : actbf;
      const unsigned short* Wlo = WzA + (size_t)(d * 4 + l) * 1024 * 1024;
      const unsigned short* Whi = WhA + (size_t)(d * 4 + l) * 1024 * 1024;
      gemm128<<<dim3(512), 512, 0, stream>>>(
          a_in, Wlo, Whi, bz + l * 1024, bh + l * 1024, 1024,
          nullptr, prebf, 2048, 1024);
      scan_p1<<<Bn * NCH * 4, 256, 0, stream>>>(prebf, Ac, Bc, d);
      scan_mid<<<16, 256, 0, stream>>>(Ac, Bc, pref);
      scan_p3<<<Bn * NCH * 4, 256, 0, stream>>>(prebf, pref, hs, d);
      if (l < Ln - 1)
        ln_kernel<<<Mn / 4, 256, 0, stream>>>(hs, (l == 0) ? nullptr : actf,
                                              gamma, beta, actf, actbf, 1024, 0);
      else
        ln_kernel<<<Mn / 4, 256, 0, stream>>>(hs, actf, gamma, beta,
                                              nullptr, combbf, 2048, d * 1024);
    }
  }
  // fusion: out = comb(bf16) @ fusion_W^T + fusion_b (f32 output)
  gemm128<<<dim3(256), 512, 0, stream>>>(
      combbf, fusWbf, fusWbf, fusion_b, fusion_b, 1 << 30, out, nullptr, 1024, 2048);
}

// Round 8
// 789.162 us; speedup vs baseline: 1.2349x; 1.2349x over previous
//
#include <hip/hip_runtime.h>
#include <stdint.h>

#define Bn 4
#define Sn 2048
#define Hn 1024
#define Ln 4
#define Mn (Bn*Sn)          // 8192 rows
#define CHUNK 32
#define NCH (Sn/CHUNK)      // 64

typedef __bf16 bf16x8 __attribute__((ext_vector_type(8)));
typedef float  f32x4  __attribute__((ext_vector_type(4)));
typedef uint32_t u32;

__device__ __forceinline__ unsigned short f2bf(float f) {
  uint32_t u = __float_as_uint(f);
  uint32_t r = (u + 0x7FFFu + ((u >> 16) & 1u)) >> 16;
  return (unsigned short)r;
}
__device__ __forceinline__ float bf2f(unsigned short u) {
  return __uint_as_float(((uint32_t)u) << 16);
}

__device__ __forceinline__ void gload_lds16(const void* g, void* l) {
  __builtin_amdgcn_global_load_lds((const __attribute__((address_space(1))) void*)g,
                                   (__attribute__((address_space(3))) void*)l, 16, 0, 0);
}

// ---------------- cast f32 -> bf16 (vectorized) ----------------
__global__ __launch_bounds__(256) void cast_f32_bf16(const float* __restrict__ src,
                                                     unsigned short* __restrict__ dst, int n4) {
  int i = blockIdx.x * 256 + threadIdx.x;
  if (i >= n4) return;
  float4 v = reinterpret_cast<const float4*>(src)[i];
  ushort4 o;
  o.x = f2bf(v.x); o.y = f2bf(v.y); o.z = f2bf(v.z); o.w = f2bf(v.w);
  reinterpret_cast<ushort4*>(dst)[i] = o;
}

// ---------------- GEMM: out[M,N] = act[M,K](bf16) @ W[N,K]^T (bf16) + bias ----------------
// ROUND-8: gemm_t<MF> — MF = M-fragments per wave. MF=8 is the round-6 gemm256
// EXACTLY (256x256, BK=64, best measured 57 us; round-7's BK=32/BN=128 variant
// quadrupled FETCH via half-cacheline reads + L2 thrash and is abandoned).
// MF=4 (BM=128, same BK=64 full-line staging, same schedule) exists solely so the
// FUSION gemm runs 64x4 = 256 blocks: the BM=256 fusion ran 128 blocks = half the
// machine idle. Schedule per K-tile (round-6 verified): STG -> asm ds_read_b128
// (invisible to waitcnt-pass alias analysis) -> counted LGKM ladder interleaved
// with setprio'd MFMA -> one vmcnt(0) + one barrier. 2-way slot-XOR swizzle
// (0 bank conflicts), linear DMA dest + inverse-permuted global source (rule #21),
// sched_barrier(0) after every waitcnt (rule #18). K-ascending accumulation ->
// bit-identical to prior rounds.

#define DSR(d, b, imm) \
  asm volatile("ds_read_b128 %0, %1 offset:%c2" : "=&v"(d) : "v"(b), "i"(imm))

#define VMW(n) do { \
    asm volatile("s_waitcnt vmcnt(" #n ")"); \
    __builtin_amdgcn_sched_barrier(0); \
  } while (0)

#define LGKM(n) do { \
    asm volatile("s_waitcnt lgkmcnt(" #n ")"); \
    __builtin_amdgcn_sched_barrier(0); \
  } while (0)

#define DSR4(ARR, base, off) do { \
    DSR(ARR[0], base, (off)); \
    DSR(ARR[1], base, (off) + 1024); \
    DSR(ARR[2], base, (off) + 2048); \
    DSR(ARR[3], base, (off) + 3072); \
  } while (0)

#define CL(ARR, BARR, MB) do { \
    __builtin_amdgcn_s_setprio(1); \
    _Pragma("unroll") \
    for (int _m = 0; _m < 4; ++_m) { \
      _Pragma("unroll") \
      for (int _n = 0; _n < 4; ++_n) \
        acc[(MB) + _m][_n] = __builtin_amdgcn_mfma_f32_16x16x32_bf16( \
            ARR[_m], BARR[_n], acc[(MB) + _m][_n], 0, 0, 0); \
    } \
    __builtin_amdgcn_s_setprio(0); \
  } while (0)

// MF=8 body: round-6 4-step LGKM ladder. MF=4 body: 2-step (aA/b0 then aB=khi A, b1).
#define BODY(buf) do { \
    if constexpr (MF == 8) { \
      DSR4(aA, baseA, ((buf) * 2 + 0) * RGA); \
      DSR4(b0, baseB, ((buf) * 2 + 0) * 16384); \
      DSR4(aB, baseA, ((buf) * 2 + 0) * RGA + 4096); \
      LGKM(4); \
      CL(aA, b0, 0); \
      DSR4(b1, baseB, ((buf) * 2 + 1) * 16384); \
      LGKM(4); \
      CL(aB, b0, 4); \
      DSR4(aA, baseA, ((buf) * 2 + 1) * RGA); \
      LGKM(4); \
      DSR4(aB, baseA, ((buf) * 2 + 1) * RGA + 4096); \
      LGKM(4); \
      CL(aA, b1, 0); \
      LGKM(0); \
      CL(aB, b1, 4); \
    } else { \
      DSR4(aA, baseA, ((buf) * 2 + 0) * RGA); \
      DSR4(b0, baseB, ((buf) * 2 + 0) * 16384); \
      DSR4(aB, baseA, ((buf) * 2 + 1) * RGA); \
      LGKM(4); \
      CL(aA, b0, 0); \
      DSR4(b1, baseB, ((buf) * 2 + 1) * 16384); \
      LGKM(0); \
      CL(aB, b1, 0); \
    } \
  } while (0)

template<int MF>
__global__ __launch_bounds__(512, 2) void gemm_t(
    const unsigned short* __restrict__ act,  // M x K
    const unsigned short* __restrict__ Wlo,  // rows [0, Nsplit)
    const unsigned short* __restrict__ Whi,  // rows [Nsplit, N)
    const float* __restrict__ bias0, const float* __restrict__ bias1,
    int Nsplit, float* __restrict__ out, unsigned short* __restrict__ outbf,
    int Ndim, int K) {
  constexpr int BMR = MF * 32;            // 256 or 128 rows
  constexpr int RGA = BMR * 64;           // A (buf,kh)-region bytes: 16384 or 8192
  __shared__ unsigned char smA[4 * RGA];
  __shared__ unsigned char smB[65536];
  const int tid  = threadIdx.x;
  const int lane = tid & 63;
  const int w    = tid >> 6;           // 0..7
  const int waveM = w >> 2;            // 0..1
  const int waveN = w & 3;             // 0..3  (64 cols each)
  const int bm = blockIdx.x, bn = blockIdx.y;

  const unsigned short* Wp; int nbase;
  if (bn * 256 < Nsplit) { Wp = Wlo; nbase = bn * 256; }
  else                   { Wp = Whi; nbase = bn * 256 - Nsplit; }

  // per-lane ds_read byte offsets within a (buf,kh) region
  const int swz  = (((lane >> 4) ^ ((lane >> 1) & 3)) << 4);
  const int aoff = (waveM * (MF * 16) + (lane & 15)) * 64 + swz;
  const int boff = (waveN * 64 + (lane & 15)) * 64 + swz;

  const u32 baseA = (u32)(size_t)(void*)&smA[0] + (u32)aoff;
  const u32 baseB = (u32)(size_t)(void*)&smB[0] + (u32)boff;

  // staging: thread -> phys (row = half*128 + (tid>>2), slot = tid&3); fetch the
  // logical slot that belongs at that phys position: log = phys ^ ((row>>1)&3)
  const int srow = tid >> 2;
  const int slog = (tid & 3) ^ ((srow >> 1) & 3);
  const unsigned short* aS0 = act + (size_t)(bm * BMR + srow) * K + slog * 8;
  const unsigned short* aS1 = aS0 + (size_t)128 * K;   // used only when MF==8
  const unsigned short* bS0 = Wp  + (size_t)(nbase + srow) * K + slog * 8;
  const unsigned short* bS1 = bS0 + (size_t)128 * K;
  const int wB = w * 1024;             // wave-uniform LDS byte base within an 8KB round

  f32x4 acc[MF][4];
#pragma unroll
  for (int m = 0; m < MF; ++m)
#pragma unroll
    for (int n = 0; n < 4; ++n) acc[m][n] = (f32x4)0.0f;

  bf16x8 aA[4], aB[4], b0[4], b1[4];

  auto STG4 = [&](int t, int buf) {
#pragma unroll
    for (int kh = 0; kh < 2; ++kh) {
      unsigned char* ra = smA + (buf * 2 + kh) * RGA;
      gload_lds16(aS0 + (size_t)t * 64 + kh * 32, ra + wB);
      if constexpr (MF == 8)
        gload_lds16(aS1 + (size_t)t * 64 + kh * 32, ra + 8192 + wB);
      unsigned char* rb = smB + (buf * 2 + kh) * 16384;
      gload_lds16(bS0 + (size_t)t * 64 + kh * 32, rb + wB);
      gload_lds16(bS1 + (size_t)t * 64 + kh * 32, rb + 8192 + wB);
    }
  };

  const int nkt   = K >> 6;   // K-tiles (even)
  const int niter = nkt >> 1;

  STG4(0, 0);
  VMW(0);
  __builtin_amdgcn_s_barrier();

  for (int j = 0; j < niter - 1; ++j) {
    STG4(2 * j + 1, 1); BODY(0); VMW(0); __builtin_amdgcn_s_barrier();
    STG4(2 * j + 2, 0); BODY(1); VMW(0); __builtin_amdgcn_s_barrier();
  }
  STG4(nkt - 1, 1); BODY(0); VMW(0); __builtin_amdgcn_s_barrier();
  BODY(1);

  const int colBase = bn * 256 + waveN * 64;
  const int rowBase = bm * BMR + waveM * (MF * 16);
#pragma unroll
  for (int m = 0; m < MF; ++m) {
#pragma unroll
    for (int n = 0; n < 4; ++n) {
      int col = colBase + n * 16 + (lane & 15);
      float bv = (col < Nsplit) ? bias0[col] : bias1[col - Nsplit];
      if (outbf) {
#pragma unroll
        for (int r = 0; r < 4; ++r) {
          int row = rowBase + m * 16 + (lane >> 4) * 4 + r;
          outbf[(size_t)row * Ndim + col] = f2bf(acc[m][n][r] + bv);
        }
      } else {
#pragma unroll
        for (int r = 0; r < 4; ++r) {
          int row = rowBase + m * 16 + (lane >> 4) * 4 + r;
          out[(size_t)row * Ndim + col] = acc[m][n][r] + bv;
        }
      }
    }
  }
}

// ---------------- pointwise helpers ----------------
__device__ __forceinline__ void gate_ab(float zp, float hp, float& a, float& bv) {
  float z  = 1.0f / (1.0f + __expf(-zp));
  float e  = __expf(-2.0f * fabsf(hp));
  float th = (1.0f - e) / (1.0f + e);
  th = (hp >= 0.0f) ? th : -th;
  a  = fminf(fmaxf(1.0f - z, 1e-8f), 1.0f - 1e-8f);
  bv = z * th;
}

// ---------------- scan pass 1: per-chunk composition (bf16 pre) ----------------
__global__ __launch_bounds__(256) void scan_p1(const unsigned short* __restrict__ pre,
                                               float* __restrict__ Ac, float* __restrict__ Bc,
                                               int dir) {
  int tid = threadIdx.x;
  int bid = blockIdx.x;
  int ht = bid & 3;
  int c  = (bid >> 2) & (NCH - 1);
  int b  = bid >> 8;
  int h  = ht * 256 + tid;
  float Aa = 1.0f, Bb = 0.0f;
  for (int j = 0; j < CHUNK; ++j) {
    int t = c * CHUNK + j;
    int s = dir ? (Sn - 1 - t) : t;
    const unsigned short* p = pre + (size_t)(b * Sn + s) * 2048;
    float a, bv;
    gate_ab(bf2f(p[h]), bf2f(p[1024 + h]), a, bv);
    Aa = a * Aa;
    Bb = a * Bb + bv;
  }
  Ac[(size_t)(b * NCH + c) * Hn + h] = Aa;
  Bc[(size_t)(b * NCH + c) * Hn + h] = Bb;
}

// ---------------- scan mid: prefix across chunks ----------------
__global__ __launch_bounds__(256) void scan_mid(const float* __restrict__ Ac,
                                                const float* __restrict__ Bc,
                                                float* __restrict__ pref) {
  int tid = blockIdx.x * 256 + threadIdx.x;
  int b = tid >> 10;
  int h = tid & 1023;
  float run = 0.0f;
  for (int c = 0; c < NCH; ++c) {
    size_t idx = (size_t)(b * NCH + c) * Hn + h;
    pref[idx] = run;
    run = Ac[idx] * run + Bc[idx];
  }
}

// ---------------- scan pass 3: apply (bf16 pre, bf16 hs out) ----------------
// ROUND-8: hs stored bf16 — halves p3 write + ln read (32 MB/layer-dir saved).
__global__ __launch_bounds__(256) void scan_p3(const unsigned short* __restrict__ pre,
                                               const float* __restrict__ pref,
                                               unsigned short* __restrict__ hs, int dir) {
  int tid = threadIdx.x;
  int bid = blockIdx.x;
  int ht = bid & 3;
  int c  = (bid >> 2) & (NCH - 1);
  int b  = bid >> 8;
  int h  = ht * 256 + tid;
  float hprev = pref[(size_t)(b * NCH + c) * Hn + h];
  for (int j = 0; j < CHUNK; ++j) {
    int t = c * CHUNK + j;
    int s = dir ? (Sn - 1 - t) : t;
    const unsigned short* p = pre + (size_t)(b * Sn + s) * 2048;
    float a, bv;
    gate_ab(bf2f(p[h]), bf2f(p[1024 + h]), a, bv);
    hprev = a * hprev + bv;
    hs[(size_t)(b * Sn + s) * Hn + h] = f2bf(hprev);
  }
}

// ---------------- LayerNorm (+residual), reads bf16 hs, writes f32 + bf16 ----------------
__global__ __launch_bounds__(256) void ln_kernel(const unsigned short* __restrict__ hs,
                                                 const float* __restrict__ resid,
                                                 const float* __restrict__ gamma,
                                                 const float* __restrict__ beta,
                                                 float* __restrict__ out_f32,
                                                 unsigned short* __restrict__ out_bf,
                                                 int bf_stride, int bf_off) {
  int row  = blockIdx.x * 4 + (threadIdx.x >> 6);
  int lane = threadIdx.x & 63;
  const ushort4* hr = reinterpret_cast<const ushort4*>(hs + (size_t)row * Hn);
  const float4* rr = resid ? reinterpret_cast<const float4*>(resid + (size_t)row * Hn) : nullptr;
  float v[16];
  float s1 = 0.0f, s2 = 0.0f;
#pragma unroll
  for (int j = 0; j < 4; ++j) {
    ushort4 t4 = hr[j * 64 + lane];
    float tx = bf2f(t4.x), ty = bf2f(t4.y), tz = bf2f(t4.z), tw = bf2f(t4.w);
    if (rr) {
      float4 q = rr[j * 64 + lane];
      tx += q.x; ty += q.y; tz += q.z; tw += q.w;
    }
    v[j*4+0] = tx; v[j*4+1] = ty; v[j*4+2] = tz; v[j*4+3] = tw;
    s1 += tx + ty + tz + tw;
    s2 += tx*tx + ty*ty + tz*tz + tw*tw;
  }
#pragma unroll
  for (int off = 1; off < 64; off <<= 1) {
    s1 += __shfl_xor(s1, off);
    s2 += __shfl_xor(s2, off);
  }
  float mu  = s1 * (1.0f / Hn);
  float var = s2 * (1.0f / Hn) - mu * mu;
  float rs  = rsqrtf(var + 1e-5f);
#pragma unroll
  for (int j = 0; j < 4; ++j) {
    float4 g  = reinterpret_cast<const float4*>(gamma)[j * 64 + lane];
    float4 be = reinterpret_cast<const float4*>(beta)[j * 64 + lane];
    float4 o;
    o.x = (v[j*4+0] - mu) * rs * g.x + be.x;
    o.y = (v[j*4+1] - mu) * rs * g.y + be.y;
    o.z = (v[j*4+2] - mu) * rs * g.z + be.z;
    o.w = (v[j*4+3] - mu) * rs * g.w + be.w;
    if (out_f32)
      reinterpret_cast<float4*>(out_f32 + (size_t)row * Hn)[j * 64 + lane] = o;
    ushort4 ob;
    ob.x = f2bf(o.x); ob.y = f2bf(o.y); ob.z = f2bf(o.z); ob.w = f2bf(o.w);
    reinterpret_cast<ushort4*>(out_bf + (size_t)row * bf_stride + bf_off)[j * 64 + lane] = ob;
  }
}

// ---------------- launcher ----------------
extern "C" void kernel_launch(void* const* d_in, const int* in_sizes, int n_in,
                              void* d_out, int out_size, void* d_ws, size_t ws_size,
                              hipStream_t stream) {
  const float* x        = (const float*)d_in[0];
  const float* fwd_Wz   = (const float*)d_in[1];
  const float* fwd_bz   = (const float*)d_in[2];
  const float* fwd_Wh   = (const float*)d_in[3];
  const float* fwd_bh   = (const float*)d_in[4];
  const float* bwd_Wz   = (const float*)d_in[5];
  const float* bwd_bz   = (const float*)d_in[6];
  const float* bwd_Wh   = (const float*)d_in[7];
  const float* bwd_bh   = (const float*)d_in[8];
  const float* fusion_W = (const float*)d_in[9];
  const float* fusion_b = (const float*)d_in[10];
  const float* gamma    = (const float*)d_in[11];
  const float* beta     = (const float*)d_in[12];
  float* out = (float*)d_out;

  // workspace layout (pre + hs slots hold bf16 now)
  unsigned short* WzA    = (unsigned short*)d_ws;              // 2*4*1024*1024
  unsigned short* WhA    = WzA + 8ULL * 1024 * 1024;           // 2*4*1024*1024
  unsigned short* fusWbf = WhA + 8ULL * 1024 * 1024;           // 1024*2048
  unsigned short* xbf    = fusWbf + 2ULL * 1024 * 1024;        // 8192*1024
  unsigned short* actbf  = xbf + 8ULL * 1024 * 1024;           // 8192*1024
  unsigned short* combbf = actbf + 8ULL * 1024 * 1024;         // 8192*2048
  float* actf = (float*)(combbf + 16ULL * 1024 * 1024);        // 8192*1024
  float* pre  = actf + 8ULL * 1024 * 1024;                     // 8192*2048 (bf16 uses half)
  float* hs   = pre + 16ULL * 1024 * 1024;                     // 8192*1024 (bf16 uses half)
  float* Ac   = hs + 8ULL * 1024 * 1024;                       // 4*NCH*1024
  float* Bc   = Ac + (size_t)Bn * NCH * Hn;
  float* pref = Bc + (size_t)Bn * NCH * Hn;
  size_t need = (size_t)((char*)(pref + (size_t)Bn * NCH * Hn) - (char*)d_ws);
  if (ws_size < need) return;
  unsigned short* prebf = (unsigned short*)pre;
  unsigned short* hsbf  = (unsigned short*)hs;

  auto cast = [&](const float* src, unsigned short* dst, size_t n) {
    int n4 = (int)(n / 4);
    cast_f32_bf16<<<(n4 + 255) / 256, 256, 0, stream>>>(src, dst, n4);
  };
  cast(fwd_Wz, WzA,                     4ULL * 1024 * 1024);
  cast(bwd_Wz, WzA + 4ULL * 1024 * 1024, 4ULL * 1024 * 1024);
  cast(fwd_Wh, WhA,                     4ULL * 1024 * 1024);
  cast(bwd_Wh, WhA + 4ULL * 1024 * 1024, 4ULL * 1024 * 1024);
  cast(fusion_W, fusWbf, 2ULL * 1024 * 1024);
  cast(x, xbf, 8ULL * 1024 * 1024);

  for (int d = 0; d < 2; ++d) {
    const float* bz = d ? bwd_bz : fwd_bz;
    const float* bh = d ? bwd_bh : fwd_bh;
    for (int l = 0; l < Ln; ++l) {
      const unsigned short* a_in = (l == 0) ? xbf : actbf;
      const unsigned short* Wlo = WzA + (size_t)(d * 4 + l) * 1024 * 1024;
      const unsigned short* Whi = WhA + (size_t)(d * 4 + l) * 1024 * 1024;
      gemm_t<8><<<dim3(Mn / 256, 2048 / 256), 512, 0, stream>>>(
          a_in, Wlo, Whi, bz + l * 1024, bh + l * 1024, 1024,
          nullptr, prebf, 2048, 1024);
      scan_p1<<<Bn * NCH * 4, 256, 0, stream>>>(prebf, Ac, Bc, d);
      scan_mid<<<16, 256, 0, stream>>>(Ac, Bc, pref);
      scan_p3<<<Bn * NCH * 4, 256, 0, stream>>>(prebf, pref, hsbf, d);
      if (l < Ln - 1)
        ln_kernel<<<Mn / 4, 256, 0, stream>>>(hsbf, (l == 0) ? nullptr : actf,
                                              gamma, beta, actf, actbf, 1024, 0);
      else
        ln_kernel<<<Mn / 4, 256, 0, stream>>>(hsbf, actf, gamma, beta,
                                              nullptr, combbf, 2048, d * 1024);
    }
  }
  // fusion: out = comb(bf16) @ fusion_W^T + fusion_b (f32 output, BM=128 -> 256 blocks)
  gemm_t<4><<<dim3(Mn / 128, 1024 / 256), 512, 0, stream>>>(
      combbf, fusWbf, fusWbf, fusion_b, fusion_b, 1 << 30, out, nullptr, 1024, 2048);
}

// Round 9
// 779.248 us; speedup vs baseline: 1.2506x; 1.0127x over previous
//
#include <hip/hip_runtime.h>
#include <stdint.h>

#define Bn 4
#define Sn 2048
#define Hn 1024
#define Ln 4
#define Mn (Bn*Sn)          // 8192 rows
#define CHUNK 32
#define NCH (Sn/CHUNK)      // 64

typedef __bf16 bf16x8 __attribute__((ext_vector_type(8)));
typedef float  f32x4  __attribute__((ext_vector_type(4)));
typedef uint32_t u32;

__device__ __forceinline__ unsigned short f2bf(float f) {
  uint32_t u = __float_as_uint(f);
  uint32_t r = (u + 0x7FFFu + ((u >> 16) & 1u)) >> 16;
  return (unsigned short)r;
}
__device__ __forceinline__ float bf2f(unsigned short u) {
  return __uint_as_float(((uint32_t)u) << 16);
}

__device__ __forceinline__ void gload_lds16(const void* g, void* l) {
  __builtin_amdgcn_global_load_lds((const __attribute__((address_space(1))) void*)g,
                                   (__attribute__((address_space(3))) void*)l, 16, 0, 0);
}

// ---------------- cast f32 -> bf16 (vectorized) ----------------
__global__ __launch_bounds__(256) void cast_f32_bf16(const float* __restrict__ src,
                                                     unsigned short* __restrict__ dst, int n4) {
  int i = blockIdx.x * 256 + threadIdx.x;
  if (i >= n4) return;
  float4 v = reinterpret_cast<const float4*>(src)[i];
  ushort4 o;
  o.x = f2bf(v.x); o.y = f2bf(v.y); o.z = f2bf(v.z); o.w = f2bf(v.w);
  reinterpret_cast<ushort4*>(dst)[i] = o;
}

// ---------------- GEMM: out[M,N] = act[M,K](bf16) @ W[N,K]^T (bf16) + bias ----------------
// UNCHANGED from round-8 (measured: layer ~42.5 us / 810 TF, fusion ~43 us).
// gemm_t<8>: 256x256 BK=64; gemm_t<4>: 128x256 so the fusion runs 256 blocks.
// Schedule per K-tile: STG -> asm ds_read_b128 -> counted LGKM ladder + setprio'd
// MFMA -> one vmcnt(0) + one barrier. 2-way slot-XOR swizzle (0 conflicts).

#define DSR(d, b, imm) \
  asm volatile("ds_read_b128 %0, %1 offset:%c2" : "=&v"(d) : "v"(b), "i"(imm))

#define VMW(n) do { \
    asm volatile("s_waitcnt vmcnt(" #n ")"); \
    __builtin_amdgcn_sched_barrier(0); \
  } while (0)

#define LGKM(n) do { \
    asm volatile("s_waitcnt lgkmcnt(" #n ")"); \
    __builtin_amdgcn_sched_barrier(0); \
  } while (0)

#define DSR4(ARR, base, off) do { \
    DSR(ARR[0], base, (off)); \
    DSR(ARR[1], base, (off) + 1024); \
    DSR(ARR[2], base, (off) + 2048); \
    DSR(ARR[3], base, (off) + 3072); \
  } while (0)

#define CL(ARR, BARR, MB) do { \
    __builtin_amdgcn_s_setprio(1); \
    _Pragma("unroll") \
    for (int _m = 0; _m < 4; ++_m) { \
      _Pragma("unroll") \
      for (int _n = 0; _n < 4; ++_n) \
        acc[(MB) + _m][_n] = __builtin_amdgcn_mfma_f32_16x16x32_bf16( \
            ARR[_m], BARR[_n], acc[(MB) + _m][_n], 0, 0, 0); \
    } \
    __builtin_amdgcn_s_setprio(0); \
  } while (0)

#define BODY(buf) do { \
    if constexpr (MF == 8) { \
      DSR4(aA, baseA, ((buf) * 2 + 0) * RGA); \
      DSR4(b0, baseB, ((buf) * 2 + 0) * 16384); \
      DSR4(aB, baseA, ((buf) * 2 + 0) * RGA + 4096); \
      LGKM(4); \
      CL(aA, b0, 0); \
      DSR4(b1, baseB, ((buf) * 2 + 1) * 16384); \
      LGKM(4); \
      CL(aB, b0, 4); \
      DSR4(aA, baseA, ((buf) * 2 + 1) * RGA); \
      LGKM(4); \
      DSR4(aB, baseA, ((buf) * 2 + 1) * RGA + 4096); \
      LGKM(4); \
      CL(aA, b1, 0); \
      LGKM(0); \
      CL(aB, b1, 4); \
    } else { \
      DSR4(aA, baseA, ((buf) * 2 + 0) * RGA); \
      DSR4(b0, baseB, ((buf) * 2 + 0) * 16384); \
      DSR4(aB, baseA, ((buf) * 2 + 1) * RGA); \
      LGKM(4); \
      CL(aA, b0, 0); \
      DSR4(b1, baseB, ((buf) * 2 + 1) * 16384); \
      LGKM(0); \
      CL(aB, b1, 0); \
    } \
  } while (0)

template<int MF>
__global__ __launch_bounds__(512, 2) void gemm_t(
    const unsigned short* __restrict__ act,  // M x K
    const unsigned short* __restrict__ Wlo,  // rows [0, Nsplit)
    const unsigned short* __restrict__ Whi,  // rows [Nsplit, N)
    const float* __restrict__ bias0, const float* __restrict__ bias1,
    int Nsplit, float* __restrict__ out, unsigned short* __restrict__ outbf,
    int Ndim, int K) {
  constexpr int BMR = MF * 32;            // 256 or 128 rows
  constexpr int RGA = BMR * 64;           // A (buf,kh)-region bytes: 16384 or 8192
  __shared__ unsigned char smA[4 * RGA];
  __shared__ unsigned char smB[65536];
  const int tid  = threadIdx.x;
  const int lane = tid & 63;
  const int w    = tid >> 6;           // 0..7
  const int waveM = w >> 2;            // 0..1
  const int waveN = w & 3;             // 0..3  (64 cols each)
  const int bm = blockIdx.x, bn = blockIdx.y;

  const unsigned short* Wp; int nbase;
  if (bn * 256 < Nsplit) { Wp = Wlo; nbase = bn * 256; }
  else                   { Wp = Whi; nbase = bn * 256 - Nsplit; }

  const int swz  = (((lane >> 4) ^ ((lane >> 1) & 3)) << 4);
  const int aoff = (waveM * (MF * 16) + (lane & 15)) * 64 + swz;
  const int boff = (waveN * 64 + (lane & 15)) * 64 + swz;

  const u32 baseA = (u32)(size_t)(void*)&smA[0] + (u32)aoff;
  const u32 baseB = (u32)(size_t)(void*)&smB[0] + (u32)boff;

  const int srow = tid >> 2;
  const int slog = (tid & 3) ^ ((srow >> 1) & 3);
  const unsigned short* aS0 = act + (size_t)(bm * BMR + srow) * K + slog * 8;
  const unsigned short* aS1 = aS0 + (size_t)128 * K;   // used only when MF==8
  const unsigned short* bS0 = Wp  + (size_t)(nbase + srow) * K + slog * 8;
  const unsigned short* bS1 = bS0 + (size_t)128 * K;
  const int wB = w * 1024;

  f32x4 acc[MF][4];
#pragma unroll
  for (int m = 0; m < MF; ++m)
#pragma unroll
    for (int n = 0; n < 4; ++n) acc[m][n] = (f32x4)0.0f;

  bf16x8 aA[4], aB[4], b0[4], b1[4];

  auto STG4 = [&](int t, int buf) {
#pragma unroll
    for (int kh = 0; kh < 2; ++kh) {
      unsigned char* ra = smA + (buf * 2 + kh) * RGA;
      gload_lds16(aS0 + (size_t)t * 64 + kh * 32, ra + wB);
      if constexpr (MF == 8)
        gload_lds16(aS1 + (size_t)t * 64 + kh * 32, ra + 8192 + wB);
      unsigned char* rb = smB + (buf * 2 + kh) * 16384;
      gload_lds16(bS0 + (size_t)t * 64 + kh * 32, rb + wB);
      gload_lds16(bS1 + (size_t)t * 64 + kh * 32, rb + 8192 + wB);
    }
  };

  const int nkt   = K >> 6;   // K-tiles (even)
  const int niter = nkt >> 1;

  STG4(0, 0);
  VMW(0);
  __builtin_amdgcn_s_barrier();

  for (int j = 0; j < niter - 1; ++j) {
    STG4(2 * j + 1, 1); BODY(0); VMW(0); __builtin_amdgcn_s_barrier();
    STG4(2 * j + 2, 0); BODY(1); VMW(0); __builtin_amdgcn_s_barrier();
  }
  STG4(nkt - 1, 1); BODY(0); VMW(0); __builtin_amdgcn_s_barrier();
  BODY(1);

  const int colBase = bn * 256 + waveN * 64;
  const int rowBase = bm * BMR + waveM * (MF * 16);
#pragma unroll
  for (int m = 0; m < MF; ++m) {
#pragma unroll
    for (int n = 0; n < 4; ++n) {
      int col = colBase + n * 16 + (lane & 15);
      float bv = (col < Nsplit) ? bias0[col] : bias1[col - Nsplit];
      if (outbf) {
#pragma unroll
        for (int r = 0; r < 4; ++r) {
          int row = rowBase + m * 16 + (lane >> 4) * 4 + r;
          outbf[(size_t)row * Ndim + col] = f2bf(acc[m][n][r] + bv);
        }
      } else {
#pragma unroll
        for (int r = 0; r < 4; ++r) {
          int row = rowBase + m * 16 + (lane >> 4) * 4 + r;
          out[(size_t)row * Ndim + col] = acc[m][n][r] + bv;
        }
      }
    }
  }
}

// ---------------- pointwise helpers ----------------
__device__ __forceinline__ void gate_ab(float zp, float hp, float& a, float& bv) {
  float z  = 1.0f / (1.0f + __expf(-zp));
  float e  = __expf(-2.0f * fabsf(hp));
  float th = (1.0f - e) / (1.0f + e);
  th = (hp >= 0.0f) ? th : -th;
  a  = fminf(fmaxf(1.0f - z, 1e-8f), 1.0f - 1e-8f);
  bv = z * th;
}

// ---------------- scan pass 1: per-chunk composition (bf16 pre) ----------------
__global__ __launch_bounds__(256) void scan_p1(const unsigned short* __restrict__ pre,
                                               float* __restrict__ Ac, float* __restrict__ Bc,
                                               int dir) {
  int tid = threadIdx.x;
  int bid = blockIdx.x;
  int ht = bid & 3;
  int c  = (bid >> 2) & (NCH - 1);
  int b  = bid >> 8;
  int h  = ht * 256 + tid;
  float Aa = 1.0f, Bb = 0.0f;
  for (int j = 0; j < CHUNK; ++j) {
    int t = c * CHUNK + j;
    int s = dir ? (Sn - 1 - t) : t;
    const unsigned short* p = pre + (size_t)(b * Sn + s) * 2048;
    float a, bv;
    gate_ab(bf2f(p[h]), bf2f(p[1024 + h]), a, bv);
    Aa = a * Aa;
    Bb = a * Bb + bv;
  }
  Ac[(size_t)(b * NCH + c) * Hn + h] = Aa;
  Bc[(size_t)(b * NCH + c) * Hn + h] = Bb;
}

// ---------------- scan mid: prefix across chunks ----------------
__global__ __launch_bounds__(256) void scan_mid(const float* __restrict__ Ac,
                                                const float* __restrict__ Bc,
                                                float* __restrict__ pref) {
  int tid = blockIdx.x * 256 + threadIdx.x;
  int b = tid >> 10;
  int h = tid & 1023;
  float run = 0.0f;
  for (int c = 0; c < NCH; ++c) {
    size_t idx = (size_t)(b * NCH + c) * Hn + h;
    pref[idx] = run;
    run = Ac[idx] * run + Bc[idx];
  }
}

// ---------------- scan pass 3 FUSED with LayerNorm (round-9) ----------------
// Round-5's fusion failed on 32 per-step block barriers. This version: scan phase
// is barrier-free (thread h owns column h; 32 steps; hs row -> LDS as bf16, same
// f2bf rounding as the round-8 global hs). ONE __syncthreads. LN phase: 16 waves
// x 2 rows each, wave-local shuffle reduction only — no more block barriers.
// Eliminates the hs global round-trip (33.5 MB/layer-dir) and 8 ln dispatches.
// resid may alias out_f32 (lane reads its 16 values before writing the same 16).
__global__ __launch_bounds__(1024) void scan_p3_ln(
    const unsigned short* __restrict__ pre, const float* __restrict__ pref,
    const float* __restrict__ resid,
    const float* __restrict__ gamma, const float* __restrict__ beta,
    float* __restrict__ out_f32, unsigned short* __restrict__ out_bf,
    int bf_stride, int bf_off, int dir) {
  __shared__ unsigned short hsl[CHUNK][Hn];   // 64 KB
  const int h = threadIdx.x;
  const int c = blockIdx.x & (NCH - 1);
  const int b = blockIdx.x >> 6;              // NCH = 64
  float hprev = pref[(size_t)(b * NCH + c) * Hn + h];

  // ---- scan phase (no barriers) ----
  for (int j = 0; j < CHUNK; ++j) {
    int t = c * CHUNK + j;
    int s = dir ? (Sn - 1 - t) : t;
    const unsigned short* p = pre + (size_t)(b * Sn + s) * 2048;
    float a, bv;
    gate_ab(bf2f(p[h]), bf2f(p[1024 + h]), a, bv);
    hprev = a * hprev + bv;
    hsl[j][h] = f2bf(hprev);
  }
  __syncthreads();

  // ---- LN phase: wave w handles rows 2w, 2w+1; lane owns h = lane*16..+15 ----
  const int lane = h & 63;
  const int wv   = h >> 6;
  // per-lane gamma/beta (uniform across rows)
  float gm[16], bt[16];
#pragma unroll
  for (int i = 0; i < 4; ++i) {
    float4 g4 = reinterpret_cast<const float4*>(gamma)[lane * 4 + i];
    float4 b4 = reinterpret_cast<const float4*>(beta)[lane * 4 + i];
    gm[i*4+0] = g4.x; gm[i*4+1] = g4.y; gm[i*4+2] = g4.z; gm[i*4+3] = g4.w;
    bt[i*4+0] = b4.x; bt[i*4+1] = b4.y; bt[i*4+2] = b4.z; bt[i*4+3] = b4.w;
  }

  for (int rr = 0; rr < 2; ++rr) {
    const int j = wv * 2 + rr;
    const int t = c * CHUNK + j;
    const int s = dir ? (Sn - 1 - t) : t;
    const size_t row = (size_t)(b * Sn + s);

    // unpack lane's 16 bf16 hs values from LDS
    const uint4* rp = reinterpret_cast<const uint4*>(&hsl[j][0]);
    uint4 q0 = rp[lane * 2], q1 = rp[lane * 2 + 1];
    uint32_t uw[8] = {q0.x, q0.y, q0.z, q0.w, q1.x, q1.y, q1.z, q1.w};
    float v[16];
#pragma unroll
    for (int k = 0; k < 8; ++k) {
      v[2*k]   = bf2f((unsigned short)(uw[k] & 0xffffu));
      v[2*k+1] = bf2f((unsigned short)(uw[k] >> 16));
    }
    if (resid) {
      const float4* rf = reinterpret_cast<const float4*>(resid + row * Hn);
#pragma unroll
      for (int i = 0; i < 4; ++i) {
        float4 r4 = rf[lane * 4 + i];
        v[i*4+0] += r4.x; v[i*4+1] += r4.y; v[i*4+2] += r4.z; v[i*4+3] += r4.w;
      }
    }
    float s1 = 0.0f, s2 = 0.0f;
#pragma unroll
    for (int m = 0; m < 16; ++m) { s1 += v[m]; s2 += v[m] * v[m]; }
#pragma unroll
    for (int off = 1; off < 64; off <<= 1) {
      s1 += __shfl_xor(s1, off);
      s2 += __shfl_xor(s2, off);
    }
    float mu  = s1 * (1.0f / Hn);
    float var = s2 * (1.0f / Hn) - mu * mu;
    float rs  = rsqrtf(var + 1e-5f);

    float o[16];
#pragma unroll
    for (int m = 0; m < 16; ++m) o[m] = (v[m] - mu) * rs * gm[m] + bt[m];

    if (out_f32) {
      float4* of = reinterpret_cast<float4*>(out_f32 + row * Hn);
#pragma unroll
      for (int i = 0; i < 4; ++i)
        of[lane * 4 + i] = make_float4(o[i*4+0], o[i*4+1], o[i*4+2], o[i*4+3]);
    }
    uint4* ob = reinterpret_cast<uint4*>(out_bf + row * bf_stride + bf_off);
    uint4 w0, w1;
    w0.x = f2bf(o[0])  | ((u32)f2bf(o[1])  << 16);
    w0.y = f2bf(o[2])  | ((u32)f2bf(o[3])  << 16);
    w0.z = f2bf(o[4])  | ((u32)f2bf(o[5])  << 16);
    w0.w = f2bf(o[6])  | ((u32)f2bf(o[7])  << 16);
    w1.x = f2bf(o[8])  | ((u32)f2bf(o[9])  << 16);
    w1.y = f2bf(o[10]) | ((u32)f2bf(o[11]) << 16);
    w1.z = f2bf(o[12]) | ((u32)f2bf(o[13]) << 16);
    w1.w = f2bf(o[14]) | ((u32)f2bf(o[15]) << 16);
    ob[lane * 2]     = w0;
    ob[lane * 2 + 1] = w1;
  }
}

// ---------------- launcher ----------------
extern "C" void kernel_launch(void* const* d_in, const int* in_sizes, int n_in,
                              void* d_out, int out_size, void* d_ws, size_t ws_size,
                              hipStream_t stream) {
  const float* x        = (const float*)d_in[0];
  const float* fwd_Wz   = (const float*)d_in[1];
  const float* fwd_bz   = (const float*)d_in[2];
  const float* fwd_Wh   = (const float*)d_in[3];
  const float* fwd_bh   = (const float*)d_in[4];
  const float* bwd_Wz   = (const float*)d_in[5];
  const float* bwd_bz   = (const float*)d_in[6];
  const float* bwd_Wh   = (const float*)d_in[7];
  const float* bwd_bh   = (const float*)d_in[8];
  const float* fusion_W = (const float*)d_in[9];
  const float* fusion_b = (const float*)d_in[10];
  const float* gamma    = (const float*)d_in[11];
  const float* beta     = (const float*)d_in[12];
  float* out = (float*)d_out;

  // workspace layout (pre bf16; hs slot now unused)
  unsigned short* WzA    = (unsigned short*)d_ws;              // 2*4*1024*1024
  unsigned short* WhA    = WzA + 8ULL * 1024 * 1024;           // 2*4*1024*1024
  unsigned short* fusWbf = WhA + 8ULL * 1024 * 1024;           // 1024*2048
  unsigned short* xbf    = fusWbf + 2ULL * 1024 * 1024;        // 8192*1024
  unsigned short* actbf  = xbf + 8ULL * 1024 * 1024;           // 8192*1024
  unsigned short* combbf = actbf + 8ULL * 1024 * 1024;         // 8192*2048
  float* actf = (float*)(combbf + 16ULL * 1024 * 1024);        // 8192*1024
  float* pre  = actf + 8ULL * 1024 * 1024;                     // 8192*2048 (bf16 uses half)
  float* hs   = pre + 16ULL * 1024 * 1024;                     // unused (kept for layout)
  float* Ac   = hs + 8ULL * 1024 * 1024;                       // 4*NCH*1024
  float* Bc   = Ac + (size_t)Bn * NCH * Hn;
  float* pref = Bc + (size_t)Bn * NCH * Hn;
  size_t need = (size_t)((char*)(pref + (size_t)Bn * NCH * Hn) - (char*)d_ws);
  if (ws_size < need) return;
  unsigned short* prebf = (unsigned short*)pre;

  auto cast = [&](const float* src, unsigned short* dst, size_t n) {
    int n4 = (int)(n / 4);
    cast_f32_bf16<<<(n4 + 255) / 256, 256, 0, stream>>>(src, dst, n4);
  };
  cast(fwd_Wz, WzA,                     4ULL * 1024 * 1024);
  cast(bwd_Wz, WzA + 4ULL * 1024 * 1024, 4ULL * 1024 * 1024);
  cast(fwd_Wh, WhA,                     4ULL * 1024 * 1024);
  cast(bwd_Wh, WhA + 4ULL * 1024 * 1024, 4ULL * 1024 * 1024);
  cast(fusion_W, fusWbf, 2ULL * 1024 * 1024);
  cast(x, xbf, 8ULL * 1024 * 1024);

  for (int d = 0; d < 2; ++d) {
    const float* bz = d ? bwd_bz : fwd_bz;
    const float* bh = d ? bwd_bh : fwd_bh;
    for (int l = 0; l < Ln; ++l) {
      const unsigned short* a_in = (l == 0) ? xbf : actbf;
      const unsigned short* Wlo = WzA + (size_t)(d * 4 + l) * 1024 * 1024;
      const unsigned short* Whi = WhA + (size_t)(d * 4 + l) * 1024 * 1024;
      gemm_t<8><<<dim3(Mn / 256, 2048 / 256), 512, 0, stream>>>(
          a_in, Wlo, Whi, bz + l * 1024, bh + l * 1024, 1024,
          nullptr, prebf, 2048, 1024);
      scan_p1<<<Bn * NCH * 4, 256, 0, stream>>>(prebf, Ac, Bc, d);
      scan_mid<<<16, 256, 0, stream>>>(Ac, Bc, pref);
      if (l < Ln - 1)
        scan_p3_ln<<<Bn * NCH, 1024, 0, stream>>>(
            prebf, pref, (l == 0) ? nullptr : actf, gamma, beta,
            actf, actbf, 1024, 0, d);
      else
        scan_p3_ln<<<Bn * NCH, 1024, 0, stream>>>(
            prebf, pref, actf, gamma, beta,
            nullptr, combbf, 2048, d * 1024, d);
    }
  }
  // fusion: out = comb(bf16) @ fusion_W^T + fusion_b (f32 output, BM=128 -> 256 blocks)
  gemm_t<4><<<dim3(Mn / 128, 1024 / 256), 512, 0, stream>>>(
      combbf, fusWbf, fusWbf, fusion_b, fusion_b, 1 << 30, out, nullptr, 1024, 2048);
}

// Round 10
// 710.498 us; speedup vs baseline: 1.3716x; 1.0968x over previous
//
#include <hip/hip_runtime.h>
#include <stdint.h>

#define Bn 4
#define Sn 2048
#define Hn 1024
#define Ln 4
#define Mn (Bn*Sn)          // 8192 rows
#define CHUNK 32
#define NCH (Sn/CHUNK)      // 64

typedef __bf16 bf16x8 __attribute__((ext_vector_type(8)));
typedef float  f32x4  __attribute__((ext_vector_type(4)));
typedef uint32_t u32;

__device__ __forceinline__ unsigned short f2bf(float f) {
  uint32_t u = __float_as_uint(f);
  uint32_t r = (u + 0x7FFFu + ((u >> 16) & 1u)) >> 16;
  return (unsigned short)r;
}
__device__ __forceinline__ float bf2f(unsigned short u) {
  return __uint_as_float(((uint32_t)u) << 16);
}

__device__ __forceinline__ void gload_lds16(const void* g, void* l) {
  __builtin_amdgcn_global_load_lds((const __attribute__((address_space(1))) void*)g,
                                   (__attribute__((address_space(3))) void*)l, 16, 0, 0);
}

// ---------------- cast f32 -> bf16 (vectorized) ----------------
__global__ __launch_bounds__(256) void cast_f32_bf16(const float* __restrict__ src,
                                                     unsigned short* __restrict__ dst, int n4) {
  int i = blockIdx.x * 256 + threadIdx.x;
  if (i >= n4) return;
  float4 v = reinterpret_cast<const float4*>(src)[i];
  ushort4 o;
  o.x = f2bf(v.x); o.y = f2bf(v.y); o.z = f2bf(v.z); o.w = f2bf(v.w);
  reinterpret_cast<ushort4*>(dst)[i] = o;
}

// ---------------- GEMM: out[M,N] = act[M,K](bf16) @ W[N,K]^T (bf16) + bias ----------------
// UNCHANGED from round-8/9 (measured: layer ~42.5 us / 810 TF, fusion ~43 us —
// at the m248 reference level for this K=1024 shape; schedule re-rolls frozen).

#define DSR(d, b, imm) \
  asm volatile("ds_read_b128 %0, %1 offset:%c2" : "=&v"(d) : "v"(b), "i"(imm))

#define VMW(n) do { \
    asm volatile("s_waitcnt vmcnt(" #n ")"); \
    __builtin_amdgcn_sched_barrier(0); \
  } while (0)

#define LGKM(n) do { \
    asm volatile("s_waitcnt lgkmcnt(" #n ")"); \
    __builtin_amdgcn_sched_barrier(0); \
  } while (0)

#define DSR4(ARR, base, off) do { \
    DSR(ARR[0], base, (off)); \
    DSR(ARR[1], base, (off) + 1024); \
    DSR(ARR[2], base, (off) + 2048); \
    DSR(ARR[3], base, (off) + 3072); \
  } while (0)

#define CL(ARR, BARR, MB) do { \
    __builtin_amdgcn_s_setprio(1); \
    _Pragma("unroll") \
    for (int _m = 0; _m < 4; ++_m) { \
      _Pragma("unroll") \
      for (int _n = 0; _n < 4; ++_n) \
        acc[(MB) + _m][_n] = __builtin_amdgcn_mfma_f32_16x16x32_bf16( \
            ARR[_m], BARR[_n], acc[(MB) + _m][_n], 0, 0, 0); \
    } \
    __builtin_amdgcn_s_setprio(0); \
  } while (0)

#define BODY(buf) do { \
    if constexpr (MF == 8) { \
      DSR4(aA, baseA, ((buf) * 2 + 0) * RGA); \
      DSR4(b0, baseB, ((buf) * 2 + 0) * 16384); \
      DSR4(aB, baseA, ((buf) * 2 + 0) * RGA + 4096); \
      LGKM(4); \
      CL(aA, b0, 0); \
      DSR4(b1, baseB, ((buf) * 2 + 1) * 16384); \
      LGKM(4); \
      CL(aB, b0, 4); \
      DSR4(aA, baseA, ((buf) * 2 + 1) * RGA); \
      LGKM(4); \
      DSR4(aB, baseA, ((buf) * 2 + 1) * RGA + 4096); \
      LGKM(4); \
      CL(aA, b1, 0); \
      LGKM(0); \
      CL(aB, b1, 4); \
    } else { \
      DSR4(aA, baseA, ((buf) * 2 + 0) * RGA); \
      DSR4(b0, baseB, ((buf) * 2 + 0) * 16384); \
      DSR4(aB, baseA, ((buf) * 2 + 1) * RGA); \
      LGKM(4); \
      CL(aA, b0, 0); \
      DSR4(b1, baseB, ((buf) * 2 + 1) * 16384); \
      LGKM(0); \
      CL(aB, b1, 0); \
    } \
  } while (0)

template<int MF>
__global__ __launch_bounds__(512, 2) void gemm_t(
    const unsigned short* __restrict__ act,  // M x K
    const unsigned short* __restrict__ Wlo,  // rows [0, Nsplit)
    const unsigned short* __restrict__ Whi,  // rows [Nsplit, N)
    const float* __restrict__ bias0, const float* __restrict__ bias1,
    int Nsplit, float* __restrict__ out, unsigned short* __restrict__ outbf,
    int Ndim, int K) {
  constexpr int BMR = MF * 32;            // 256 or 128 rows
  constexpr int RGA = BMR * 64;           // A (buf,kh)-region bytes: 16384 or 8192
  __shared__ unsigned char smA[4 * RGA];
  __shared__ unsigned char smB[65536];
  const int tid  = threadIdx.x;
  const int lane = tid & 63;
  const int w    = tid >> 6;           // 0..7
  const int waveM = w >> 2;            // 0..1
  const int waveN = w & 3;             // 0..3  (64 cols each)
  const int bm = blockIdx.x, bn = blockIdx.y;

  const unsigned short* Wp; int nbase;
  if (bn * 256 < Nsplit) { Wp = Wlo; nbase = bn * 256; }
  else                   { Wp = Whi; nbase = bn * 256 - Nsplit; }

  const int swz  = (((lane >> 4) ^ ((lane >> 1) & 3)) << 4);
  const int aoff = (waveM * (MF * 16) + (lane & 15)) * 64 + swz;
  const int boff = (waveN * 64 + (lane & 15)) * 64 + swz;

  const u32 baseA = (u32)(size_t)(void*)&smA[0] + (u32)aoff;
  const u32 baseB = (u32)(size_t)(void*)&smB[0] + (u32)boff;

  const int srow = tid >> 2;
  const int slog = (tid & 3) ^ ((srow >> 1) & 3);
  const unsigned short* aS0 = act + (size_t)(bm * BMR + srow) * K + slog * 8;
  const unsigned short* aS1 = aS0 + (size_t)128 * K;   // used only when MF==8
  const unsigned short* bS0 = Wp  + (size_t)(nbase + srow) * K + slog * 8;
  const unsigned short* bS1 = bS0 + (size_t)128 * K;
  const int wB = w * 1024;

  f32x4 acc[MF][4];
#pragma unroll
  for (int m = 0; m < MF; ++m)
#pragma unroll
    for (int n = 0; n < 4; ++n) acc[m][n] = (f32x4)0.0f;

  bf16x8 aA[4], aB[4], b0[4], b1[4];

  auto STG4 = [&](int t, int buf) {
#pragma unroll
    for (int kh = 0; kh < 2; ++kh) {
      unsigned char* ra = smA + (buf * 2 + kh) * RGA;
      gload_lds16(aS0 + (size_t)t * 64 + kh * 32, ra + wB);
      if constexpr (MF == 8)
        gload_lds16(aS1 + (size_t)t * 64 + kh * 32, ra + 8192 + wB);
      unsigned char* rb = smB + (buf * 2 + kh) * 16384;
      gload_lds16(bS0 + (size_t)t * 64 + kh * 32, rb + wB);
      gload_lds16(bS1 + (size_t)t * 64 + kh * 32, rb + 8192 + wB);
    }
  };

  const int nkt   = K >> 6;   // K-tiles (even)
  const int niter = nkt >> 1;

  STG4(0, 0);
  VMW(0);
  __builtin_amdgcn_s_barrier();

  for (int j = 0; j < niter - 1; ++j) {
    STG4(2 * j + 1, 1); BODY(0); VMW(0); __builtin_amdgcn_s_barrier();
    STG4(2 * j + 2, 0); BODY(1); VMW(0); __builtin_amdgcn_s_barrier();
  }
  STG4(nkt - 1, 1); BODY(0); VMW(0); __builtin_amdgcn_s_barrier();
  BODY(1);

  const int colBase = bn * 256 + waveN * 64;
  const int rowBase = bm * BMR + waveM * (MF * 16);
#pragma unroll
  for (int m = 0; m < MF; ++m) {
#pragma unroll
    for (int n = 0; n < 4; ++n) {
      int col = colBase + n * 16 + (lane & 15);
      float bv = (col < Nsplit) ? bias0[col] : bias1[col - Nsplit];
      if (outbf) {
#pragma unroll
        for (int r = 0; r < 4; ++r) {
          int row = rowBase + m * 16 + (lane >> 4) * 4 + r;
          outbf[(size_t)row * Ndim + col] = f2bf(acc[m][n][r] + bv);
        }
      } else {
#pragma unroll
        for (int r = 0; r < 4; ++r) {
          int row = rowBase + m * 16 + (lane >> 4) * 4 + r;
          out[(size_t)row * Ndim + col] = acc[m][n][r] + bv;
        }
      }
    }
  }
}

// ---------------- pointwise helpers ----------------
__device__ __forceinline__ void gate_ab(float zp, float hp, float& a, float& bv) {
  float z  = 1.0f / (1.0f + __expf(-zp));
  float e  = __expf(-2.0f * fabsf(hp));
  float th = (1.0f - e) / (1.0f + e);
  th = (hp >= 0.0f) ? th : -th;
  a  = fminf(fmaxf(1.0f - z, 1e-8f), 1.0f - 1e-8f);
  bv = z * th;
}

// ---------------- scan pass 1: per-chunk composition (bf16 pre) ----------------
__global__ __launch_bounds__(256) void scan_p1(const unsigned short* __restrict__ pre,
                                               float* __restrict__ Ac, float* __restrict__ Bc,
                                               int dir) {
  int tid = threadIdx.x;
  int bid = blockIdx.x;
  int ht = bid & 3;
  int c  = (bid >> 2) & (NCH - 1);
  int b  = bid >> 8;
  int h  = ht * 256 + tid;
  float Aa = 1.0f, Bb = 0.0f;
  for (int j = 0; j < CHUNK; ++j) {
    int t = c * CHUNK + j;
    int s = dir ? (Sn - 1 - t) : t;
    const unsigned short* p = pre + (size_t)(b * Sn + s) * 2048;
    float a, bv;
    gate_ab(bf2f(p[h]), bf2f(p[1024 + h]), a, bv);
    Aa = a * Aa;
    Bb = a * Bb + bv;
  }
  Ac[(size_t)(b * NCH + c) * Hn + h] = Aa;
  Bc[(size_t)(b * NCH + c) * Hn + h] = Bb;
}

// ---------------- scan mid: prefix across chunks ----------------
__global__ __launch_bounds__(256) void scan_mid(const float* __restrict__ Ac,
                                                const float* __restrict__ Bc,
                                                float* __restrict__ pref) {
  int tid = blockIdx.x * 256 + threadIdx.x;
  int b = tid >> 10;
  int h = tid & 1023;
  float run = 0.0f;
  for (int c = 0; c < NCH; ++c) {
    size_t idx = (size_t)(b * NCH + c) * Hn + h;
    pref[idx] = run;
    run = Ac[idx] * run + Bc[idx];
  }
}

// ---------------- scan pass 3 FUSED with LayerNorm (round-10) ----------------
// Changes vs round-9:
//  * SINGLE bf16 activation stream: resid input is bf16 (the same buffer the
//    previous layer's LN wrote as the GEMM input); the duplicate f32 actf write
//    (33.5 MB) and f32 resid read are eliminated. Traffic 117 -> 67 MB/dispatch.
//    Aliasing (resid == out_bf for middle layers) is safe: each row is read and
//    then written by the SAME wave, per-thread read-before-write.
//  * LN-phase lane->h map: lane owns h in {lane*8..+7} u {512+lane*8..+7} so the
//    two ds_read_b128 per row are lane-contiguous (2-way bank aliasing = free;
//    the round-9 32B-stride map was 4-way). All gamma/resid/out accesses are
//    16B-vectorized with the same split.
__global__ __launch_bounds__(1024) void scan_p3_ln(
    const unsigned short* __restrict__ pre, const float* __restrict__ pref,
    const unsigned short* __restrict__ resid,   // bf16; may be null; may alias out_bf
    const float* __restrict__ gamma, const float* __restrict__ beta,
    unsigned short* __restrict__ out_bf,
    int bf_stride, int bf_off, int dir) {
  __shared__ unsigned short hsl[CHUNK][Hn];   // 64 KB
  const int h = threadIdx.x;
  const int c = blockIdx.x & (NCH - 1);
  const int b = blockIdx.x >> 6;              // NCH = 64
  float hprev = pref[(size_t)(b * NCH + c) * Hn + h];

  // ---- scan phase (no barriers) ----
  for (int j = 0; j < CHUNK; ++j) {
    int t = c * CHUNK + j;
    int s = dir ? (Sn - 1 - t) : t;
    const unsigned short* p = pre + (size_t)(b * Sn + s) * 2048;
    float a, bv;
    gate_ab(bf2f(p[h]), bf2f(p[1024 + h]), a, bv);
    hprev = a * hprev + bv;
    hsl[j][h] = f2bf(hprev);
  }
  __syncthreads();

  // ---- LN phase: wave wv handles rows 2wv, 2wv+1 ----
  const int lane = h & 63;
  const int wv   = h >> 6;
  // per-lane gamma/beta: [lane*8..+7] and [512+lane*8..+7]
  float gm[16], bt[16];
  {
    const float4* gp = reinterpret_cast<const float4*>(gamma);
    const float4* bp = reinterpret_cast<const float4*>(beta);
#pragma unroll
    for (int half = 0; half < 2; ++half) {
      int base = half * 128 + lane * 2;
#pragma unroll
      for (int i = 0; i < 2; ++i) {
        float4 g4 = gp[base + i], b4 = bp[base + i];
        int o = half * 8 + i * 4;
        gm[o+0] = g4.x; gm[o+1] = g4.y; gm[o+2] = g4.z; gm[o+3] = g4.w;
        bt[o+0] = b4.x; bt[o+1] = b4.y; bt[o+2] = b4.z; bt[o+3] = b4.w;
      }
    }
  }

  for (int rr = 0; rr < 2; ++rr) {
    const int j = wv * 2 + rr;
    const int t = c * CHUNK + j;
    const int s = dir ? (Sn - 1 - t) : t;
    const size_t row = (size_t)(b * Sn + s);

    // lane's 16 bf16 hs values from LDS (two contiguous-16B reads, 2-way free)
    const uint4* rp = reinterpret_cast<const uint4*>(&hsl[j][0]);
    uint4 q0 = rp[lane], q1 = rp[64 + lane];
    uint32_t uw[8] = {q0.x, q0.y, q0.z, q0.w, q1.x, q1.y, q1.z, q1.w};
    float v[16];
#pragma unroll
    for (int k = 0; k < 8; ++k) {
      v[2*k]   = bf2f((unsigned short)(uw[k] & 0xffffu));
      v[2*k+1] = bf2f((unsigned short)(uw[k] >> 16));
    }
    if (resid) {
      const uint4* rf = reinterpret_cast<const uint4*>(resid + row * Hn);
      uint4 r0 = rf[lane], r1 = rf[64 + lane];
      uint32_t rw[8] = {r0.x, r0.y, r0.z, r0.w, r1.x, r1.y, r1.z, r1.w};
#pragma unroll
      for (int k = 0; k < 8; ++k) {
        v[2*k]   += bf2f((unsigned short)(rw[k] & 0xffffu));
        v[2*k+1] += bf2f((unsigned short)(rw[k] >> 16));
      }
    }
    float s1 = 0.0f, s2 = 0.0f;
#pragma unroll
    for (int m = 0; m < 16; ++m) { s1 += v[m]; s2 += v[m] * v[m]; }
#pragma unroll
    for (int off = 1; off < 64; off <<= 1) {
      s1 += __shfl_xor(s1, off);
      s2 += __shfl_xor(s2, off);
    }
    float mu  = s1 * (1.0f / Hn);
    float var = s2 * (1.0f / Hn) - mu * mu;
    float rs  = rsqrtf(var + 1e-5f);

    float o[16];
#pragma unroll
    for (int m = 0; m < 16; ++m) o[m] = (v[m] - mu) * rs * gm[m] + bt[m];

    uint4* ob = reinterpret_cast<uint4*>(out_bf + row * bf_stride + bf_off);
    uint4 w0, w1;
    w0.x = f2bf(o[0])  | ((u32)f2bf(o[1])  << 16);
    w0.y = f2bf(o[2])  | ((u32)f2bf(o[3])  << 16);
    w0.z = f2bf(o[4])  | ((u32)f2bf(o[5])  << 16);
    w0.w = f2bf(o[6])  | ((u32)f2bf(o[7])  << 16);
    w1.x = f2bf(o[8])  | ((u32)f2bf(o[9])  << 16);
    w1.y = f2bf(o[10]) | ((u32)f2bf(o[11]) << 16);
    w1.z = f2bf(o[12]) | ((u32)f2bf(o[13]) << 16);
    w1.w = f2bf(o[14]) | ((u32)f2bf(o[15]) << 16);
    ob[lane]      = w0;
    ob[64 + lane] = w1;
  }
}

// ---------------- launcher ----------------
extern "C" void kernel_launch(void* const* d_in, const int* in_sizes, int n_in,
                              void* d_out, int out_size, void* d_ws, size_t ws_size,
                              hipStream_t stream) {
  const float* x        = (const float*)d_in[0];
  const float* fwd_Wz   = (const float*)d_in[1];
  const float* fwd_bz   = (const float*)d_in[2];
  const float* fwd_Wh   = (const float*)d_in[3];
  const float* fwd_bh   = (const float*)d_in[4];
  const float* bwd_Wz   = (const float*)d_in[5];
  const float* bwd_bz   = (const float*)d_in[6];
  const float* bwd_Wh   = (const float*)d_in[7];
  const float* bwd_bh   = (const float*)d_in[8];
  const float* fusion_W = (const float*)d_in[9];
  const float* fusion_b = (const float*)d_in[10];
  const float* gamma    = (const float*)d_in[11];
  const float* beta     = (const float*)d_in[12];
  float* out = (float*)d_out;

  // workspace layout (pre bf16; actf/hs slots retained but unused)
  unsigned short* WzA    = (unsigned short*)d_ws;              // 2*4*1024*1024
  unsigned short* WhA    = WzA + 8ULL * 1024 * 1024;           // 2*4*1024*1024
  unsigned short* fusWbf = WhA + 8ULL * 1024 * 1024;           // 1024*2048
  unsigned short* xbf    = fusWbf + 2ULL * 1024 * 1024;        // 8192*1024
  unsigned short* actbf  = xbf + 8ULL * 1024 * 1024;           // 8192*1024 (GEMM in + resid)
  unsigned short* combbf = actbf + 8ULL * 1024 * 1024;         // 8192*2048
  float* actf = (float*)(combbf + 16ULL * 1024 * 1024);        // unused (layout keep)
  float* pre  = actf + 8ULL * 1024 * 1024;                     // 8192*2048 (bf16 uses half)
  float* hs   = pre + 16ULL * 1024 * 1024;                     // unused (layout keep)
  float* Ac   = hs + 8ULL * 1024 * 1024;                       // 4*NCH*1024
  float* Bc   = Ac + (size_t)Bn * NCH * Hn;
  float* pref = Bc + (size_t)Bn * NCH * Hn;
  size_t need = (size_t)((char*)(pref + (size_t)Bn * NCH * Hn) - (char*)d_ws);
  if (ws_size < need) return;
  unsigned short* prebf = (unsigned short*)pre;

  auto cast = [&](const float* src, unsigned short* dst, size_t n) {
    int n4 = (int)(n / 4);
    cast_f32_bf16<<<(n4 + 255) / 256, 256, 0, stream>>>(src, dst, n4);
  };
  cast(fwd_Wz, WzA,                     4ULL * 1024 * 1024);
  cast(bwd_Wz, WzA + 4ULL * 1024 * 1024, 4ULL * 1024 * 1024);
  cast(fwd_Wh, WhA,                     4ULL * 1024 * 1024);
  cast(bwd_Wh, WhA + 4ULL * 1024 * 1024, 4ULL * 1024 * 1024);
  cast(fusion_W, fusWbf, 2ULL * 1024 * 1024);
  cast(x, xbf, 8ULL * 1024 * 1024);

  for (int d = 0; d < 2; ++d) {
    const float* bz = d ? bwd_bz : fwd_bz;
    const float* bh = d ? bwd_bh : fwd_bh;
    for (int l = 0; l < Ln; ++l) {
      const unsigned short* a_in = (l == 0) ? xbf : actbf;
      const unsigned short* Wlo = WzA + (size_t)(d * 4 + l) * 1024 * 1024;
      const unsigned short* Whi = WhA + (size_t)(d * 4 + l) * 1024 * 1024;
      gemm_t<8><<<dim3(Mn / 256, 2048 / 256), 512, 0, stream>>>(
          a_in, Wlo, Whi, bz + l * 1024, bh + l * 1024, 1024,
          nullptr, prebf, 2048, 1024);
      scan_p1<<<Bn * NCH * 4, 256, 0, stream>>>(prebf, Ac, Bc, d);
      scan_mid<<<16, 256, 0, stream>>>(Ac, Bc, pref);
      if (l < Ln - 1)
        scan_p3_ln<<<Bn * NCH, 1024, 0, stream>>>(
            prebf, pref, (l == 0) ? nullptr : actbf, gamma, beta,
            actbf, 1024, 0, d);
      else
        scan_p3_ln<<<Bn * NCH, 1024, 0, stream>>>(
            prebf, pref, actbf, gamma, beta,
            combbf, 2048, d * 1024, d);
    }
  }
  // fusion: out = comb(bf16) @ fusion_W^T + fusion_b (f32 output, BM=128 -> 256 blocks)
  gemm_t<4><<<dim3(Mn / 128, 1024 / 256), 512, 0, stream>>>(
      combbf, fusWbf, fusWbf, fusion_b, fusion_b, 1 << 30, out, nullptr, 1024, 2048);
}